// Round 5
// baseline (239.572 us; speedup 1.0000x reference)
//
#include <hip/hip_runtime.h>

#define DIM    2048
#define SEQ    4096
#define BATCH  4
#define KW     4
#define TCHUNK 8
#define SEGLEN 64   // timesteps owned by one thread (walked sequentially)

typedef float fvec4 __attribute__((ext_vector_type(4)));  // native vector type

constexpr int D4      = DIM / 4;                   // 512 float4 columns
constexpr int NSEG    = SEQ / SEGLEN;              // 64 segments per row
constexpr int NTHREAD = BATCH * NSEG * D4;         // 131072 threads
constexpr int BLOCKSZ = 256;
constexpr int NBLOCK  = NTHREAD / BLOCKSZ;         // 512 blocks = 2/CU
constexpr int ITERS   = SEGLEN / TCHUNK;           // 8 chunk iterations

// Long-stream steady-state version. Evidence: five burst-style variants all
// froze at 83-85us, while fillBufferAligned (same captures) streams 6.7 TB/s
// at 9.5% occupancy and m13's copy hits 6.29 TB/s -- both are few-waves x
// long-grid-stride-stream kernels. This kernel adopts that shape: each thread
// owns a 64-timestep segment of one (batch, channel-quad) row, walks time
// sequentially with the 3-tap halo carried in registers (halo re-reads drop
// 19% -> 4.7%), double-buffered 8-iteration pipeline, no sched_barriers --
// the compiler pipelines countable streaming loops well (that IS the copy).
__global__ __launch_bounds__(BLOCKSZ) void ShortConv1D_78855599554935_kernel(
    const float* __restrict__ x, const float* __restrict__ w,
    const float* __restrict__ bias, float* __restrict__ out)
{
    int idx = blockIdx.x * BLOCKSZ + threadIdx.x;
    int d4  = idx & (D4 - 1);          // fastest: wave = 64 consecutive d4 -> 1KB/instr
    int r   = idx >> 9;
    int seg = r & (NSEG - 1);          // wave-uniform
    int bb  = r >> 6;                  // wave-uniform

    const fvec4* __restrict__ x4 = (const fvec4*)x;
    const fvec4* __restrict__ w4 = (const fvec4*)w;
    const fvec4* __restrict__ b4 = (const fvec4*)bias;
    fvec4* __restrict__ o4 = (fvec4*)out;

    // weight rows for channels d = 4*d4 + j  (w is [D,K] row-major, K=4)
    fvec4 w0 = w4[d4 * 4 + 0];
    fvec4 w1 = w4[d4 * 4 + 1];
    fvec4 w2 = w4[d4 * 4 + 2];
    fvec4 w3 = w4[d4 * 4 + 3];
    fvec4 bv = b4[d4];

    long tseg = (long)seg * SEGLEN;
    long base = ((long)bb * SEQ + tseg) * D4 + d4;   // fvec4 index of x[tseg]

    // rolling halo: h0=x[t-3], h1=x[t-2], h2=x[t-1]
    fvec4 h0, h1, h2;
    if (seg > 0) {                     // wave-uniform branch
        h0 = x4[base - 3 * D4];
        h1 = x4[base - 2 * D4];
        h2 = x4[base - 1 * D4];
    } else {
        h0 = (fvec4)(0.f);
        h1 = (fvec4)(0.f);
        h2 = (fvec4)(0.f);
    }

    fvec4 bufA[TCHUNK], bufB[TCHUNK];

#define LOADCH(buf, t4)                                                       \
    do {                                                                      \
        _Pragma("unroll")                                                     \
        for (int j = 0; j < TCHUNK; ++j) (buf)[j] = x4[(t4) + j * D4];        \
    } while (0)

    // compute TCHUNK outputs from buf + rolling carry, store, advance carry
#define COMPST(buf, t4)                                                       \
    do {                                                                      \
        fvec4 v0 = h0, v1 = h1, v2 = h2;                                      \
        _Pragma("unroll")                                                     \
        for (int j = 0; j < TCHUNK; ++j) {                                    \
            fvec4 dd = (buf)[j];                                              \
            fvec4 rr;                                                         \
            rr.x = bv.x + w0.x * v0.x + w0.y * v1.x + w0.z * v2.x + w0.w * dd.x; \
            rr.y = bv.y + w1.x * v0.y + w1.y * v1.y + w1.z * v2.y + w1.w * dd.y; \
            rr.z = bv.z + w2.x * v0.z + w2.y * v1.z + w2.z * v2.z + w2.w * dd.z; \
            rr.w = bv.w + w3.x * v0.w + w3.y * v1.w + w3.z * v2.w + w3.w * dd.w; \
            o4[(t4) + j * D4] = rr;                                           \
            v0 = v1; v1 = v2; v2 = dd;                                        \
        }                                                                     \
        h0 = v0; h1 = v1; h2 = v2;                                            \
    } while (0)

    // ---- software-pipelined steady-state stream over the segment ----
    LOADCH(bufA, base);
#pragma unroll
    for (int it = 0; it < ITERS; it += 2) {
        long tA = base + (long)it * TCHUNK * D4;
        long tB = tA + TCHUNK * D4;
        if (it + 1 < ITERS) LOADCH(bufB, tB);      // prefetch next chunk
        COMPST(bufA, tA);                          // compute/store current
        if (it + 2 < ITERS) LOADCH(bufA, tB + TCHUNK * D4);
        if (it + 1 < ITERS) COMPST(bufB, tB);
    }

#undef LOADCH
#undef COMPST
}

extern "C" void kernel_launch(void* const* d_in, const int* in_sizes, int n_in,
                              void* d_out, int out_size, void* d_ws, size_t ws_size,
                              hipStream_t stream) {
    const float* x = (const float*)d_in[0];
    const float* w = (const float*)d_in[1];
    const float* b = (const float*)d_in[2];
    float* out = (float*)d_out;

    ShortConv1D_78855599554935_kernel<<<NBLOCK, BLOCKSZ, 0, stream>>>(x, w, b, out);
}